// Round 16
// baseline (78.160 us; speedup 1.0000x reference)
//
#include <hip/hip_runtime.h>

// DropGCN: out = relu( mean_r( diag(k_r) A diag(k_r) X ) @ W^T + b )
//  == Y[8192,160] = A @ Xm   (Xm[:, r*32+d] = k_r .* X[:,d], bf16)
//  then per-row masked mean over the 5 replica slices, @W^T, +b, relu.
//
// Round 16: r13 champion (68.4 us) with ONE change: K-loop unrolled by 2 and
// the A fetch for both steps issued as one contiguous 256 B/row burst (two
// consecutive 128 B lines = same DRAM page, one activation serves both).
// r15 proved latency is hidden (LDS-only barrier null) -> gemm is DRAM
// THROUGHPUT limited at ~4.6 TB/s; 128 B/page-visit is the surviving
// explanation. r7 tested bursts under the nontemporal poison (confounded).

#define N_NODES   8192
#define NSLICES   256          // 8192/32 K-slices
#define NCOLS     160          // 5 replicas * 32 dims
#define SLICE_US  5120         // ushorts per K-slice image (160*32)
#define MASK_WS   65536        // ws bytes reserved for normalized mask
#define KSPLIT    8
#define STEPS     (NSLICES / KSPLIT)   // 32 K-steps per block

typedef __attribute__((ext_vector_type(4))) float f32x4;
typedef __attribute__((ext_vector_type(8))) short bf16x8;

__device__ __forceinline__ unsigned short f2bf(float f) {
  // round-to-nearest-even f32 -> bf16 bits
  unsigned int u = __builtin_bit_cast(unsigned int, f);
  return (unsigned short)((u + 0x7FFFu + ((u >> 16) & 1u)) >> 16);
}

__device__ __forceinline__ unsigned pack_bf(float lo, float hi) {
  // two f32 -> packed bf16 pair (round-to-nearest ties-up; verified r3-r15)
  unsigned u0 = __builtin_bit_cast(unsigned, lo) + 0x8000u;
  unsigned u1 = __builtin_bit_cast(unsigned, hi) + 0x8000u;
  return (u1 & 0xFFFF0000u) | (u0 >> 16);
}

// ---------------------------------------------------------------------------
// prep (r8-verified, unchanged): block s handles K-slice s, all coalesced.
// LINEAR XmG layout: chunk c (16 B) = (n = c>>2, kg = c&3), kk = kg*8+e.
// ---------------------------------------------------------------------------
__global__ __launch_bounds__(256) void prep_kernel(
    const float* __restrict__ X, const void* __restrict__ raw,
    unsigned char* __restrict__ mk, unsigned short* __restrict__ XmG) {
  __shared__ float xt[32 * 33];   // [kk][d], pad 33
  __shared__ float mf[160];       // [r][kk] 0/1
  __shared__ int mode32s;
  const int tid = threadIdx.x;
  const int s = blockIdx.x;

  if (tid == 0) {
    const unsigned* wrd = (const unsigned*)raw;
    int ok = 1;
    for (int i = 0; i < 64; ++i) {
      unsigned v = wrd[i];
      if (!(v <= 1u || v == 0x3F800000u)) { ok = 0; break; }
    }
    mode32s = ok;
  }
  f32x4 xv = *(const f32x4*)(X + (size_t)s * 1024 + tid * 4);
  __syncthreads();
  const int mode32 = mode32s;
#pragma unroll
  for (int q = 0; q < 4; ++q) {
    int e = tid * 4 + q;                 // e = jj*32 + d
    xt[(e >> 5) * 33 + (e & 31)] = xv[q];
  }
  if (tid < 160) {
    int r = tid >> 5, jj = tid & 31;
    int gi = r * N_NODES + s * 32 + jj;
    unsigned char kv = mode32 ? (unsigned char)(((const unsigned*)raw)[gi] != 0u)
                              : (unsigned char)(((const unsigned char*)raw)[gi] != 0);
    mk[gi] = kv;
    mf[tid] = kv ? 1.0f : 0.0f;
  }
  __syncthreads();

  unsigned short* outp = XmG + (size_t)s * SLICE_US;
  for (int c = tid; c < 640; c += 256) {
    int n = c >> 2, kg = c & 3;          // LINEAR layout
    int r = n >> 5, d = n & 31;
    union { bf16x8 v; unsigned short us[8]; } o;
#pragma unroll
    for (int e = 0; e < 8; ++e) {
      int kk = kg * 8 + e;
      o.us[e] = f2bf(mf[r * 32 + kk] * xt[kk * 33 + d]);
    }
    *(bf16x8*)(outp + c * 8) = o.v;
  }
}

// ---------------------------------------------------------------------------
// gemm (r13 structure; A fetch burst-batched over 2 steps): block = 8 waves
// x 32 rows = 256 rows, all 160 cols, K-range 1024. LDS double-buffer of one
// 10 KB K-slice, 1 __syncthreads/step, reg-staged with XOR swizzle: slice
// ushort (n*32+kg*8+e) at LDS ushort n*32 + ((kg ^ ((n>>1)&3))*8) + e.
// Per superstep (2 K-steps): [pack both steps' B frags from banks]
// [burst-load banks for steps t+2,t+3: 8 plain loads covering 256 B
// contiguous per A row] [phase A: stage+MFMA+barrier] [phase B: same].
// Verified D map: acc[nt][jj] = Y[base_m + n0][nt*16 + kg*4 + jj].
// Fused replica mask-mean epilogue -> partZ[sy][m][d] f32.
// ---------------------------------------------------------------------------
__global__ __launch_bounds__(512, 2) void gemm_kernel(
    const float* __restrict__ A, const unsigned short* __restrict__ XmG,
    const unsigned char* __restrict__ mk, float* __restrict__ partZ) {
  __shared__ __align__(16) unsigned short xm[2][SLICE_US];   // 20 KB

  const int tid  = threadIdx.x;
  const int lane = tid & 63;
  const int w    = tid >> 6;        // wave 0..7
  const int n0   = lane & 15;
  const int kg   = lane >> 4;       // k-group 0..3 (8 elems each)
  const int sy   = blockIdx.y;      // k-split 0..7
  const int s_base = sy * STEPS;
  const int base_m = blockIdx.x * 256 + w * 32;   // wave owns 32 rows

  // A rows for the wave's two 16-row tiles
  const float* aptr0 =
      A + (size_t)(base_m + n0) * N_NODES + s_base * 32 + kg * 8;
  const float* aptr1 = aptr0 + (size_t)16 * N_NODES;

  // staging: thread stages chunk c0=tid (and c1=tid+512 if tid<128);
  // chunk c = 16 B at slice ushort c*8 -> n = c>>2, kgs = c&3
  const unsigned short* xsrc = XmG + (size_t)s_base * SLICE_US;
  const int c0 = tid, n_c0 = c0 >> 2;
  const int off0 = n_c0 * 32 + (((c0 & 3) ^ ((n_c0 >> 1) & 3)) << 3);
  const int c1 = tid + 512, n_c1 = c1 >> 2;
  const int off1 = n_c1 * 32 + (((c1 & 3) ^ ((n_c1 >> 1) & 3)) << 3);
  const bool has2 = (tid < 128);

  // fragment read base (swizzled slot depends only on n0,kg)
  const unsigned short* frag0 =
      &xm[0][0] + n0 * 32 + ((kg ^ ((n0 >> 1) & 3)) << 3);

  f32x4 acc0[10], acc1[10];
#pragma unroll
  for (int i = 0; i < 10; ++i) {
    acc0[i] = (f32x4){0.f, 0.f, 0.f, 0.f};
    acc1[i] = (f32x4){0.f, 0.f, 0.f, 0.f};
  }

  // A banks: steps t (e*) and t+1 (o*), per row 256 B contiguous, loaded as
  // one 8-instruction burst (per row: bytes [t*128, t*128+256) in order).
  f32x4 e0, e0b, o0, o0b, e1, e1b, o1, o1b;
#define LOAD_BURST(t0)                                                         \
  {                                                                            \
    const float* p0_ = aptr0 + (size_t)(t0)*32;                                \
    const float* p1_ = aptr1 + (size_t)(t0)*32;                                \
    e0  = *(const f32x4*)p0_;                                                  \
    e0b = *(const f32x4*)(p0_ + 4);                                            \
    o0  = *(const f32x4*)(p0_ + 32);                                           \
    o0b = *(const f32x4*)(p0_ + 36);                                           \
    e1  = *(const f32x4*)p1_;                                                  \
    e1b = *(const f32x4*)(p1_ + 4);                                            \
    o1  = *(const f32x4*)(p1_ + 32);                                           \
    o1b = *(const f32x4*)(p1_ + 36);                                           \
  }

  // Xm slice staging for step t (identical to r13's per-step code)
#define STAGE(t)                                                               \
  {                                                                            \
    if ((t) + 1 < STEPS) {                                                     \
      unsigned short* dst = &xm[cur ^ 1][0];                                   \
      *(bf16x8*)(dst + off0) = sa;                                             \
      if (has2) *(bf16x8*)(dst + off1) = sb2;                                  \
    }                                                                          \
    if ((t) + 2 < STEPS) {                                                     \
      const unsigned short* s2 = xsrc + (size_t)((t) + 2) * SLICE_US;          \
      sa = *(const bf16x8*)(s2 + c0 * 8);                                      \
      if (has2) sb2 = *(const bf16x8*)(s2 + c1 * 8);                           \
    }                                                                          \
  }

#define MFMA_PHASE(bt0, bt1)                                                   \
  {                                                                            \
    const unsigned short* fb = frag0 + cur * SLICE_US;                         \
    _Pragma("unroll") for (int nt = 0; nt < 10; ++nt) {                        \
      bf16x8 af = *(const bf16x8*)(fb + nt * 512);                             \
      acc0[nt] =                                                               \
          __builtin_amdgcn_mfma_f32_16x16x32_bf16(af, bt0.v, acc0[nt], 0, 0, 0);\
      acc1[nt] =                                                               \
          __builtin_amdgcn_mfma_f32_16x16x32_bf16(af, bt1.v, acc1[nt], 0, 0, 0);\
    }                                                                          \
  }

  // prologue: slice 0 -> regs -> LDS buf0; slice 1 -> regs; A steps 0,1 burst
  bf16x8 sa = *(const bf16x8*)(xsrc + c0 * 8);
  bf16x8 sb2 = sa;
  if (has2) sb2 = *(const bf16x8*)(xsrc + c1 * 8);
  LOAD_BURST(0);
  *(bf16x8*)(&xm[0][off0]) = sa;
  if (has2) *(bf16x8*)(&xm[0][off1]) = sb2;
  sa = *(const bf16x8*)(xsrc + SLICE_US + c0 * 8);
  if (has2) sb2 = *(const bf16x8*)(xsrc + SLICE_US + c1 * 8);
  __syncthreads();

  int cur = 0;
  for (int ss = 0; ss < STEPS / 2; ++ss) {
    const int t = 2 * ss;
    // pack both steps' B fragments from the banks (frees banks for reload)
    union { bf16x8 v; unsigned u[4]; } pb00, pb01, pb10, pb11;
    pb00.u[0] = pack_bf(e0[0], e0[1]);   pb00.u[1] = pack_bf(e0[2], e0[3]);
    pb00.u[2] = pack_bf(e0b[0], e0b[1]); pb00.u[3] = pack_bf(e0b[2], e0b[3]);
    pb01.u[0] = pack_bf(e1[0], e1[1]);   pb01.u[1] = pack_bf(e1[2], e1[3]);
    pb01.u[2] = pack_bf(e1b[0], e1b[1]); pb01.u[3] = pack_bf(e1b[2], e1b[3]);
    pb10.u[0] = pack_bf(o0[0], o0[1]);   pb10.u[1] = pack_bf(o0[2], o0[3]);
    pb10.u[2] = pack_bf(o0b[0], o0b[1]); pb10.u[3] = pack_bf(o0b[2], o0b[3]);
    pb11.u[0] = pack_bf(o1[0], o1[1]);   pb11.u[1] = pack_bf(o1[2], o1[3]);
    pb11.u[2] = pack_bf(o1b[0], o1b[1]); pb11.u[3] = pack_bf(o1b[2], o1b[3]);

    // burst-load A for steps t+2, t+3 (256 B contiguous per row)
    const int nb = (t + 2 < STEPS) ? t + 2 : t;
    LOAD_BURST(nb);

    // ---- phase A: step t on buf[cur]
    STAGE(t);
    MFMA_PHASE(pb00, pb01);
    __syncthreads();
    cur ^= 1;

    // ---- phase B: step t+1 on buf[cur]
    STAGE(t + 1);
    MFMA_PHASE(pb10, pb11);
    __syncthreads();
    cur ^= 1;
  }

  // fused replica mask-mean epilogue:
  // acc[2t][jj]  = Y[m][32t + kg*4+jj]       (d = kg*4+jj,    r = t)
  // acc[2t+1][jj]= Y[m][32t + 16 + kg*4+jj]  (d = kg*4+jj+16, r = t)
  const int m0g = base_m + n0;
  const int m1g = m0g + 16;
  float w0[5], w1[5];
#pragma unroll
  for (int t = 0; t < 5; ++t) {
    w0[t] = mk[t * N_NODES + m0g] ? 0.2f : 0.0f;
    w1[t] = mk[t * N_NODES + m1g] ? 0.2f : 0.0f;
  }
  f32x4 zA0 = (f32x4){0.f, 0.f, 0.f, 0.f}, zB0 = zA0, zA1 = zA0, zB1 = zA0;
#pragma unroll
  for (int t = 0; t < 5; ++t) {
    zA0 += w0[t] * acc0[2 * t];
    zB0 += w0[t] * acc0[2 * t + 1];
    zA1 += w1[t] * acc1[2 * t];
    zB1 += w1[t] * acc1[2 * t + 1];
  }
  float* p0 = partZ + ((size_t)sy * N_NODES + m0g) * 32 + kg * 4;
  *(f32x4*)(p0)      = zA0;
  *(f32x4*)(p0 + 16) = zB0;
  float* p1 = partZ + ((size_t)sy * N_NODES + m1g) * 32 + kg * 4;
  *(f32x4*)(p1)      = zA1;
  *(f32x4*)(p1 + 16) = zB1;
}

// ---------------------------------------------------------------------------
// epi: z[m][d] = sum_s partZ[s][m][d];  out[m][o] = relu(b[o] + z . W[o])
// ---------------------------------------------------------------------------
__global__ __launch_bounds__(64) void epi_kernel(
    const float* __restrict__ partZ, const float* __restrict__ W,
    const float* __restrict__ bias, float* __restrict__ out) {
  __shared__ float sW[1024];
  __shared__ float sb[32];
  const int tid = threadIdx.x;
  for (int i = tid; i < 1024; i += 64) sW[i] = W[i];
  if (tid < 32) sb[tid] = bias[tid];
  __syncthreads();

  const int m = blockIdx.x * 64 + tid;
  float zz[32];
#pragma unroll
  for (int i = 0; i < 32; ++i) zz[i] = 0.f;
  const float* p = partZ + (size_t)m * 32;
  for (int s = 0; s < KSPLIT; ++s) {
    const float* ps = p + (size_t)s * N_NODES * 32;
#pragma unroll
    for (int i = 0; i < 8; ++i) {
      f32x4 v = *(const f32x4*)(ps + i * 4);
      zz[4 * i + 0] += v[0]; zz[4 * i + 1] += v[1];
      zz[4 * i + 2] += v[2]; zz[4 * i + 3] += v[3];
    }
  }
#pragma unroll
  for (int o = 0; o < 32; o += 4) {
    f32x4 r;
#pragma unroll
    for (int q = 0; q < 4; ++q) {
      float a = sb[o + q];
#pragma unroll
      for (int d = 0; d < 32; ++d) a = fmaf(zz[d], sW[(o + q) * 32 + d], a);
      r[q] = fmaxf(a, 0.f);
    }
    *(f32x4*)(out + (size_t)m * 32 + o) = r;
  }
}

extern "C" void kernel_launch(void* const* d_in, const int* in_sizes, int n_in,
                              void* d_out, int out_size, void* d_ws, size_t ws_size,
                              hipStream_t stream) {
  const float* A = (const float*)d_in[0];
  const float* X = (const float*)d_in[1];
  const float* W = (const float*)d_in[2];
  const float* b = (const float*)d_in[3];
  const void*  keep_raw = (const void*)d_in[4];
  float* out = (float*)d_out;

  const size_t xm_bytes    = (size_t)NSLICES * SLICE_US * 2;       // 2,621,440
  const size_t partz_bytes = (size_t)KSPLIT * N_NODES * 32 * 4;    // 8,388,608
  if (ws_size < MASK_WS + xm_bytes + partz_bytes) return;  // need ~11 MB

  unsigned char* mk = (unsigned char*)d_ws;
  unsigned short* XmG = (unsigned short*)((char*)d_ws + MASK_WS);
  float* partZ = (float*)((char*)d_ws + MASK_WS + xm_bytes);

  prep_kernel<<<dim3(NSLICES), 256, 0, stream>>>(X, keep_raw, mk, XmG);
  gemm_kernel<<<dim3(N_NODES / 256, KSPLIT), 512, 0, stream>>>(A, XmG, mk, partZ);
  epi_kernel<<<dim3(N_NODES / 64), 64, 0, stream>>>(partZ, W, b, out);
}